// Round 17
// baseline (200.740 us; speedup 1.0000x reference)
//
#include <hip/hip_runtime.h>
#include <math.h>

#define F_IN   128
#define NCLASS 40
#define ALPHA  0.2f

typedef unsigned int  u32;
typedef unsigned short u16;

__device__ __forceinline__ float lrelu(float v){ return v > 0.0f ? v : ALPHA*v; }
__device__ __forceinline__ void fma4(float4& a, float s, const float4& w){
  a.x += s*w.x; a.y += s*w.y; a.z += s*w.z; a.w += s*w.w;
}
__device__ __forceinline__ u32 f2bf(float f){
  u32 u = __float_as_uint(f);
  return (u + 0x7fffu + ((u>>16)&1u)) >> 16;
}
__device__ __forceinline__ float bf_lo(u32 w){ return __uint_as_float(w << 16); }
__device__ __forceinline__ float bf_hi(u32 w){ return __uint_as_float(w & 0xffff0000u); }
__device__ __forceinline__ float bf1(u16 w){ return __uint_as_float(((u32)w) << 16); }

// ---- init: block0 = dtype-detect + zero done, block1 = wt precompute,
//      blocks 2.. = zero cnt. ----
__global__ void __launch_bounds__(256) k_init(
    const int* __restrict__ ei, int E, int* __restrict__ flag,
    unsigned* __restrict__ done, int* __restrict__ cnt, int N,
    const float* __restrict__ W2, const float* __restrict__ a2s,
    const float* __restrict__ a2t, float* __restrict__ wt)
{
  int b = blockIdx.x, tid = threadIdx.x;
  if (b == 0){
    __shared__ int red[4];
    int n = E < 1000 ? E : 1000;
    int c = 0;
    for (int j = tid; j < n; j += 256) c += (ei[2*j+1]==0);
    #pragma unroll
    for (int off=32; off; off>>=1) c += __shfl_xor(c, off, 64);
    if ((tid&63)==0) red[tid>>6] = c;
    __syncthreads();
    if (tid==0) *flag = (red[0]+red[1]+red[2]+red[3]) > n/2 ? 1 : 0;
    if (tid==1) *done = 0u;
  } else if (b == 1){
    if (tid < 128){
      float s = 0.f, t = 0.f;
      for (int c=0;c<NCLASS;c++){ float w = W2[tid*NCLASS+c]; s += w*a2s[c]; t += w*a2t[c]; }
      wt[tid] = s; wt[128+tid] = t;
    }
  } else {
    int base = (b-2)*1024 + tid*4;
    if (base + 3 < N) *(int4*)(cnt + base) = make_int4(0,0,0,0);
    else { for (int i=0;i<4;i++) if (base+i < N) cnt[base+i] = 0; }
  }
}

// ---- standalone hist: 4-deep batched returning atomics, no LDS, max
// occupancy. loads -> atomics (pipelined) -> stores, all straight-line. ----
__global__ void __launch_bounds__(256) k_hist(const int* __restrict__ ei,
    const int* __restrict__ flag, int* __restrict__ cnt, int* __restrict__ eoff, int E){
  int S = gridDim.x*256;
  int gid = blockIdx.x*256 + threadIdx.x;
  int i64 = *flag;
  int e0=gid, e1=gid+S, e2=gid+2*S, e3=gid+3*S;
  int t0=0,t1=0,t2=0,t3=0;
  if (e0<E) t0 = i64 ? ei[2*E+2*e0] : ei[E+e0];
  if (e1<E) t1 = i64 ? ei[2*E+2*e1] : ei[E+e1];
  if (e2<E) t2 = i64 ? ei[2*E+2*e2] : ei[E+e2];
  if (e3<E) t3 = i64 ? ei[2*E+2*e3] : ei[E+e3];
  int o0=0,o1=0,o2=0,o3=0;
  if (e0<E) o0 = atomicAdd(cnt+t0,1);
  if (e1<E) o1 = atomicAdd(cnt+t1,1);
  if (e2<E) o2 = atomicAdd(cnt+t2,1);
  if (e3<E) o3 = atomicAdd(cnt+t3,1);
  if (e0<E) eoff[e0]=o0;
  if (e1<E) eoff[e1]=o1;
  if (e2<E) eoff[e2]=o2;
  if (e3<E) eoff[e3]=o3;
  for (int e = gid+4*S; e < E; e += S){   // safety only (4S >= E normally)
    int tt = i64 ? ei[2*E+2*e] : ei[E+e];
    eoff[e] = atomicAdd(cnt+tt,1);
  }
}

// ---- single-pass scan (decoupled last-block): partial rowptr + boff. ----
__global__ void __launch_bounds__(256) k_scan(const int* __restrict__ cnt,
    int* __restrict__ rowptr, int* __restrict__ bsum, int* __restrict__ boff,
    unsigned* __restrict__ done, int N, int NB){
  __shared__ int wsum[4];
  __shared__ int lastFlag;
  int tid = threadIdx.x, lane = tid & 63, wv = tid >> 6;
  int base = blockIdx.x*1024 + tid*4;
  int4 v = make_int4(0,0,0,0);
  if (base + 3 < N) v = *(const int4*)(cnt + base);
  else {
    if (base   < N) v.x = cnt[base];
    if (base+1 < N) v.y = cnt[base+1];
    if (base+2 < N) v.z = cnt[base+2];
  }
  int tsum = v.x+v.y+v.z+v.w;
  int inc = tsum;
  #pragma unroll
  for (int off=1; off<64; off<<=1){
    int o = __shfl_up(inc, off, 64);
    if (lane >= off) inc += o;
  }
  if (lane == 63) wsum[wv] = inc;
  __syncthreads();
  int wo = 0;
  #pragma unroll
  for (int w=0; w<4; w++) wo += (w < wv) ? wsum[w] : 0;
  int ex = wo + inc - tsum;
  int4 r; r.x = ex; r.y = ex+v.x; r.z = ex+v.x+v.y; r.w = ex+v.x+v.y+v.z;
  if (base + 3 < N) *(int4*)(rowptr + base) = r;
  else {
    if (base   < N) rowptr[base]   = r.x;
    if (base+1 < N) rowptr[base+1] = r.y;
    if (base+2 < N) rowptr[base+2] = r.z;
  }
  if (tid == 0){
    bsum[blockIdx.x] = wsum[0]+wsum[1]+wsum[2]+wsum[3];
    __threadfence();
    unsigned tk = atomicAdd(done, 1u);
    lastFlag = (tk == (unsigned)(NB-1));
  }
  __syncthreads();
  if (lastFlag){
    __threadfence();
    if (tid < 64){
      int vv = tid < NB ? bsum[tid] : 0;
      int ii = vv;
      #pragma unroll
      for (int off=1; off<64; off<<=1){
        int o = __shfl_up(ii, off, 64);
        if (tid >= off) ii += o;
      }
      if (tid < NB) boff[tid] = ii - vv;
    }
  }
}

// ---- fused scatter + proj1. Scatter (atomic-free, fire-and-forget stores)
// runs as prologue; its latency hides under Ws staging + proj compute.
// Disjoint resources: scatter = VMEM, proj = VALU+LDS. ----
__global__ void __launch_bounds__(256) k_sp(
    const float* __restrict__ x, const float* __restrict__ W1,
    const float* __restrict__ a_src, const float* __restrict__ a_tgt,
    u16* __restrict__ projb, float* __restrict__ ss, float* __restrict__ st, int N,
    const int* __restrict__ ei, const int* __restrict__ flag,
    const int* __restrict__ rowptr, const int* __restrict__ boff,
    const int* __restrict__ eoff, int* __restrict__ esrc, int E)
{
  __shared__ float Ws[128*64];
  int t = threadIdx.x;
  int lb = blockIdx.y*gridDim.x + blockIdx.x;     // 0..1279
  // ---- scatter batch: 3 edges/thread; batched loads, deferred stores ----
  {
    int S = gridDim.x*gridDim.y*256;              // 327680
    int gid = lb*256 + t;
    int i64 = *flag;
    int e0=gid, e1=gid+S, e2=gid+2*S;
    int s0=0,s1=0,s2=0,t0=0,t1=0,t2=0;
    if (e0<E){ if(i64){s0=ei[2*e0];t0=ei[2*E+2*e0];}else{s0=ei[e0];t0=ei[E+e0];} }
    if (e1<E){ if(i64){s1=ei[2*e1];t1=ei[2*E+2*e1];}else{s1=ei[e1];t1=ei[E+e1];} }
    if (e2<E){ if(i64){s2=ei[2*e2];t2=ei[2*E+2*e2];}else{s2=ei[e2];t2=ei[E+e2];} }
    int p0=0,p1=0,p2=0;
    if (e0<E) p0 = rowptr[t0] + boff[t0>>10] + eoff[e0];
    if (e1<E) p1 = rowptr[t1] + boff[t1>>10] + eoff[e1];
    if (e2<E) p2 = rowptr[t2] + boff[t2>>10] + eoff[e2];
    if (e0<E) esrc[p0] = s0;
    if (e1<E) esrc[p1] = s1;
    if (e2<E) esrc[p2] = s2;
    for (int e = gid+3*S; e < E; e += S){         // safety only (3S >= E)
      int s, tt;
      if (i64){ s = ei[2*e]; tt = ei[2*E + 2*e]; }
      else    { s = ei[e];   tt = ei[E + e]; }
      esrc[rowptr[tt] + boff[tt>>10] + eoff[e]] = s;
    }
  }
  // ---- Ws staging ----
  int ybase = blockIdx.y * 64;
  for (int i = t; i < 128*64; i += 256){
    int f = i >> 6, jj = i & 63;
    int j = ybase + jj;
    Ws[i] = W1[((j>>5)<<12) + (f<<5) + (j&31)];
  }
  __syncthreads();
  // ---- proj phase ----
  int g = t & 15, slot = t >> 4;
  int col = ybase + g*4;
  float4 as = *(const float4*)(a_src + col);
  float4 at = *(const float4*)(a_tgt + col);
  for (int base = blockIdx.x*32; base < N; base += gridDim.x*32){
    int n0 = base + 2*slot, n1 = n0 + 1;
    bool v0 = n0 < N, v1 = n1 < N;
    int nc0 = v0 ? n0 : 0, nc1 = v1 ? n1 : 0;
    float4 acc0 = {0,0,0,0}, acc1 = {0,0,0,0};
    #pragma unroll 4
    for (int f = 0; f < 128; f += 4){
      float4 xa = *(const float4*)(x + (size_t)nc0*128 + f);
      float4 xb = *(const float4*)(x + (size_t)nc1*128 + f);
      const float4* wr = (const float4*)(Ws + f*64 + g*4);
      float4 w0 = wr[0], w1 = wr[16], w2 = wr[32], w3 = wr[48];
      fma4(acc0, xa.x, w0); fma4(acc0, xa.y, w1); fma4(acc0, xa.z, w2); fma4(acc0, xa.w, w3);
      fma4(acc1, xb.x, w0); fma4(acc1, xb.y, w1); fma4(acc1, xb.z, w2); fma4(acc1, xb.w, w3);
    }
    if (v0){
      uint2 p; p.x = f2bf(acc0.x) | (f2bf(acc0.y)<<16); p.y = f2bf(acc0.z) | (f2bf(acc0.w)<<16);
      *(uint2*)(projb + (size_t)n0*128 + col) = p;
    }
    if (v1){
      uint2 p; p.x = f2bf(acc1.x) | (f2bf(acc1.y)<<16); p.y = f2bf(acc1.z) | (f2bf(acc1.w)<<16);
      *(uint2*)(projb + (size_t)n1*128 + col) = p;
    }
    float ps0 = acc0.x*as.x + acc0.y*as.y + acc0.z*as.z + acc0.w*as.w;
    float pt0 = acc0.x*at.x + acc0.y*at.y + acc0.z*at.z + acc0.w*at.w;
    float ps1 = acc1.x*as.x + acc1.y*as.y + acc1.z*as.z + acc1.w*as.w;
    float pt1 = acc1.x*at.x + acc1.y*at.y + acc1.z*at.z + acc1.w*at.w;
    #pragma unroll
    for (int off=1; off<8; off<<=1){
      ps0 += __shfl_xor(ps0, off, 64); pt0 += __shfl_xor(pt0, off, 64);
      ps1 += __shfl_xor(ps1, off, 64); pt1 += __shfl_xor(pt1, off, 64);
    }
    if ((g&7)==0){
      int h = (ybase>>5) + (g>>3);
      if (v0){ ss[4*n0 + h] = ps0; st[4*n0 + h] = pt0; }
      if (v1){ ss[4*n1 + h] = ps1; st[4*n1 + h] = pt1; }
    }
  }
}

// One wave per node; lane owns cols {2*lane,2*lane+1}; 8-deep batched loads.
// Whole wave reads ONE 256B row per k-step (coalesced). Single pass (no
// segment-max: logits are O(5), exp cannot overflow). Emits ss2/st2 fused.
__global__ void __launch_bounds__(256) k_l1(
    const int* __restrict__ rowptr, const int* __restrict__ boff,
    const int* __restrict__ esrc,
    const float* __restrict__ ss, const float* __restrict__ st,
    const u16* __restrict__ projb, const float* __restrict__ b1,
    const float* __restrict__ wt, float* __restrict__ hbuf,
    float* __restrict__ ss2, float* __restrict__ st2, int N, int E)
{
  int lane = threadIdx.x & 63;
  int node = blockIdx.x*4 + (threadIdx.x>>6);
  if (node >= N) return;
  int beg = rowptr[node] + boff[node>>10];
  int np1 = node + 1;
  int end = (np1 == N) ? E : rowptr[np1] + boff[np1>>10];
  int h = lane & 3;
  float stv = st[4*node + h];
  float accx = 0.f, accy = 0.f, denom = 0.f;
  int hc = lane >> 4;
  const u16* myco = projb + 2*lane;
  for (int cbeg = beg; cbeg < end; cbeg += 16){
    int ne = end - cbeg; if (ne > 16) ne = 16;
    int e = cbeg + (lane>>2);
    float ex = 0.f; int sreg = 0;
    if (e < end){ sreg = esrc[e]; ex = __expf(lrelu(ss[4*sreg + h] + stv)); }
    denom += ex;
    if (ne == 16){
      #pragma unroll
      for (int half = 0; half < 2; ++half){
        const int kb = half*8;
        u32 w[8]; float eh[8];
        #pragma unroll
        for (int k=0;k<8;k++){
          int sl = __shfl(sreg, (kb+k)*4, 64);
          w[k] = *(const u32*)(myco + (size_t)sl*128);   // 8 loads in flight
        }
        #pragma unroll
        for (int k=0;k<8;k++) eh[k] = __shfl(ex, (kb+k)*4 + hc, 64);
        #pragma unroll
        for (int k=0;k<8;k++){ accx += bf_lo(w[k])*eh[k]; accy += bf_hi(w[k])*eh[k]; }
      }
    } else {
      for (int k=0;k<ne;k++){
        int   sl = __shfl(sreg, k*4, 64);
        float eh = __shfl(ex, k*4 + hc, 64);
        u32 w = *(const u32*)(myco + (size_t)sl*128);
        accx += bf_lo(w)*eh; accy += bf_hi(w)*eh;
      }
    }
  }
  #pragma unroll
  for (int off=4; off<64; off<<=1) denom += __shfl_xor(denom, off, 64);
  float d = __shfl(denom, hc, 64) + 1e-16f;
  float2 bb = *(const float2*)(b1 + 2*lane);
  float v0 = accx/d + bb.x;
  float v1 = accy/d + bb.y;
  float h0 = v0 > 0.f ? v0 : expm1f(v0);
  float h1 = v1 > 0.f ? v1 : expm1f(v1);
  *(float2*)(hbuf + (size_t)node*128 + 2*lane) = make_float2(h0, h1);
  float2 wsv = *(const float2*)(wt + 2*lane);
  float2 wtv = *(const float2*)(wt + 128 + 2*lane);
  float pss = h0*wsv.x + h1*wsv.y;
  float ptt = h0*wtv.x + h1*wtv.y;
  #pragma unroll
  for (int off=1; off<64; off<<=1){
    pss += __shfl_xor(pss, off, 64); ptt += __shfl_xor(ptt, off, 64);
  }
  if (lane == 0){ ss2[node] = pss; st2[node] = ptt; }
}

// Register-blocked GEMM: proj2 (bf16) = h @ W2. 20KB LDS.
__global__ void __launch_bounds__(256) k_proj2(
    const float* __restrict__ h, const float* __restrict__ W2,
    u16* __restrict__ projb2, int N)
{
  __shared__ float Ws[128*NCLASS];
  int t = threadIdx.x;
  for (int i = t; i < 128*NCLASS; i += 256) Ws[i] = W2[i];
  __syncthreads();
  if (t >= 250) return;
  int g = t % 10, slot = t / 10;
  int col = g*4;
  for (int base = blockIdx.x*50; base < N; base += gridDim.x*50){
    int n0 = base + 2*slot, n1 = n0 + 1;
    bool v0 = n0 < N, v1 = n1 < N;
    int nc0 = v0 ? n0 : 0, nc1 = v1 ? n1 : 0;
    float4 acc0 = {0,0,0,0}, acc1 = {0,0,0,0};
    #pragma unroll 4
    for (int f = 0; f < 128; f += 4){
      float4 xa = *(const float4*)(h + (size_t)nc0*128 + f);
      float4 xb = *(const float4*)(h + (size_t)nc1*128 + f);
      const float4* wr = (const float4*)(Ws + f*NCLASS + col);
      float4 w0 = wr[0], w1 = wr[10], w2 = wr[20], w3 = wr[30];
      fma4(acc0, xa.x, w0); fma4(acc0, xa.y, w1); fma4(acc0, xa.z, w2); fma4(acc0, xa.w, w3);
      fma4(acc1, xb.x, w0); fma4(acc1, xb.y, w1); fma4(acc1, xb.z, w2); fma4(acc1, xb.w, w3);
    }
    if (v0){
      uint2 p; p.x = f2bf(acc0.x) | (f2bf(acc0.y)<<16); p.y = f2bf(acc0.z) | (f2bf(acc0.w)<<16);
      *(uint2*)(projb2 + (size_t)n0*NCLASS + col) = p;
    }
    if (v1){
      uint2 p; p.x = f2bf(acc1.x) | (f2bf(acc1.y)<<16); p.y = f2bf(acc1.z) | (f2bf(acc1.w)<<16);
      *(uint2*)(projb2 + (size_t)n1*NCLASS + col) = p;
    }
  }
}

// One wave per node; lanes 0..39 own one class column; 8-deep batched loads.
__global__ void __launch_bounds__(256) k_l2(
    const int* __restrict__ rowptr, const int* __restrict__ boff,
    const int* __restrict__ esrc,
    const float* __restrict__ ss, const float* __restrict__ st,
    const u16* __restrict__ projb2, float* __restrict__ out, int N, int E)
{
  int lane = threadIdx.x & 63;
  int node = blockIdx.x*4 + (threadIdx.x>>6);
  if (node >= N) return;
  int beg = rowptr[node] + boff[node>>10];
  int np1 = node + 1;
  int end = (np1 == N) ? E : rowptr[np1] + boff[np1>>10];
  float stv = st[node];
  float acc = 0.f, denom = 0.f;
  const u16* myco = projb2 + lane;   // lanes>=40 read in-region garbage, discarded
  for (int cbeg = beg; cbeg < end; cbeg += 64){
    int ne = end - cbeg; if (ne > 64) ne = 64;
    int e = cbeg + lane;
    float ex = 0.f; int sreg = 0;
    if (e < end){ sreg = esrc[e]; ex = __expf(lrelu(ss[sreg] + stv)); }
    denom += ex;
    int k = 0;
    for (; k+8 <= ne; k += 8){
      u16 wv[8]; float ek[8];
      #pragma unroll
      for (int q=0;q<8;q++){
        int sl = __shfl(sreg, k+q, 64);
        wv[q] = myco[(size_t)sl*NCLASS];   // 8 loads in flight
      }
      #pragma unroll
      for (int q=0;q<8;q++) ek[q] = __shfl(ex, k+q, 64);
      #pragma unroll
      for (int q=0;q<8;q++) acc += bf1(wv[q])*ek[q];
    }
    for (; k < ne; k++){
      int   sl  = __shfl(sreg, k, 64);
      float exk = __shfl(ex, k, 64);
      acc += bf1(myco[(size_t)sl*NCLASS]) * exk;
    }
  }
  #pragma unroll
  for (int off=32; off; off>>=1) denom += __shfl_xor(denom, off, 64);
  float v = lane < NCLASS ? acc/(denom + 1e-16f) : -INFINITY;
  float m2 = v;
  #pragma unroll
  for (int off=32; off; off>>=1) m2 = fmaxf(m2, __shfl_xor(m2, off, 64));
  float sme = lane < NCLASS ? __expf(v - m2) : 0.f;
  #pragma unroll
  for (int off=32; off; off>>=1) sme += __shfl_xor(sme, off, 64);
  if (lane < NCLASS) out[(size_t)node*NCLASS + lane] = v - m2 - logf(sme);
}

extern "C" void kernel_launch(void* const* d_in, const int* in_sizes, int n_in,
                              void* d_out, int out_size, void* d_ws, size_t ws_size,
                              hipStream_t stream)
{
  const float* x   = (const float*)d_in[0];
  const int*   ei  = (const int*)d_in[2];
  const float* W1  = (const float*)d_in[3];
  const float* a1s = (const float*)d_in[4];
  const float* a1t = (const float*)d_in[5];
  const float* b1  = (const float*)d_in[6];
  const float* W2  = (const float*)d_in[7];
  const float* a2s = (const float*)d_in[8];
  const float* a2t = (const float*)d_in[9];
  float* out = (float*)d_out;
  const int N = in_sizes[0] / F_IN;      // 50000
  const int E = in_sizes[2] / 2;         // 800000
  const int NB = (N + 1023) / 1024;      // scan blocks (49, <=64)

  char* w = (char*)d_ws;
  float*    hbuf   = (float*)w;                        // N*128 f32
  u16*      projb  = (u16*)(hbuf + (size_t)N*128);     // N*128 bf16
  u16*      projb2 = projb;                            // N*40 bf16 (overlap)
  float*    ss1    = (float*)(projb + (size_t)N*128);  // 4N
  float*    st1    = ss1 + 4*(size_t)N;                // 4N
  float*    ss2    = st1 + 4*(size_t)N;                // N
  float*    st2    = ss2 + N;                          // N
  int*      rowptr = (int*)(st2 + N);                  // N (partial)
  int*      cnt    = rowptr + N + 4;                   // N
  int*      eoff   = cnt + N;                          // E
  int*      esrc   = eoff + E;                         // E
  int*      flag   = esrc + E;                         // 1
  float*    wt     = (float*)(flag + 4);               // 256
  int*      bsum   = (int*)(wt + 256);                 // <=64
  int*      boff   = bsum + 64;                        // <=64
  unsigned* done   = (unsigned*)(boff + 64);           // 1

  k_init<<<2+NB,256,0,stream>>>(ei, E, flag, done, cnt, N, W2, a2s, a2t, wt);
  k_hist<<<1024,256,0,stream>>>(ei, flag, cnt, eoff, E);
  k_scan<<<NB,256,0,stream>>>(cnt, rowptr, bsum, boff, done, N, NB);
  k_sp<<<dim3(640,2),256,0,stream>>>(x, W1, a1s, a1t, projb, ss1, st1, N,
                                     ei, flag, rowptr, boff, eoff, esrc, E);
  k_l1<<<(N+3)/4,256,0,stream>>>(rowptr, boff, esrc, ss1, st1, projb, b1, wt,
                                 hbuf, ss2, st2, N, E);
  k_proj2<<<(N+49)/50,256,0,stream>>>(hbuf, W2, projb2, N);
  k_l2<<<(N+3)/4,256,0,stream>>>(rowptr, boff, esrc, ss2, st2, projb2, out, N, E);
}

// Round 18
// 177.873 us; speedup vs baseline: 1.1286x; 1.1286x over previous
//
#include <hip/hip_runtime.h>
#include <math.h>

#define F_IN   128
#define NCLASS 40
#define ALPHA  0.2f
#define GRID_F1 2048   // fused proj1+hist grid: 3/4 proj1 (1536), 1/4 hist (512)

typedef unsigned int  u32;
typedef unsigned short u16;

__device__ __forceinline__ float lrelu(float v){ return v > 0.0f ? v : ALPHA*v; }
__device__ __forceinline__ void fma4(float4& a, float s, const float4& w){
  a.x += s*w.x; a.y += s*w.y; a.z += s*w.z; a.w += s*w.w;
}
__device__ __forceinline__ u32 f2bf(float f){
  u32 u = __float_as_uint(f);
  return (u + 0x7fffu + ((u>>16)&1u)) >> 16;
}
__device__ __forceinline__ float bf_lo(u32 w){ return __uint_as_float(w << 16); }
__device__ __forceinline__ float bf_hi(u32 w){ return __uint_as_float(w & 0xffff0000u); }
__device__ __forceinline__ float bf1(u16 w){ return __uint_as_float(((u32)w) << 16); }

// ---- init: block0 = dtype-detect + zero done, block1 = wt precompute,
//      blocks 2.. = zero cnt. ----
__global__ void __launch_bounds__(256) k_init(
    const int* __restrict__ ei, int E, int* __restrict__ flag,
    unsigned* __restrict__ done, int* __restrict__ cnt, int N,
    const float* __restrict__ W2, const float* __restrict__ a2s,
    const float* __restrict__ a2t, float* __restrict__ wt)
{
  int b = blockIdx.x, tid = threadIdx.x;
  if (b == 0){
    __shared__ int red[4];
    int n = E < 1000 ? E : 1000;
    int c = 0;
    for (int j = tid; j < n; j += 256) c += (ei[2*j+1]==0);
    #pragma unroll
    for (int off=32; off; off>>=1) c += __shfl_xor(c, off, 64);
    if ((tid&63)==0) red[tid>>6] = c;
    __syncthreads();
    if (tid==0) *flag = (red[0]+red[1]+red[2]+red[3]) > n/2 ? 1 : 0;
    if (tid==1) *done = 0u;
  } else if (b == 1){
    if (tid < 128){
      float s = 0.f, t = 0.f;
      for (int c=0;c<NCLASS;c++){ float w = W2[tid*NCLASS+c]; s += w*a2s[c]; t += w*a2t[c]; }
      wt[tid] = s; wt[128+tid] = t;
    }
  } else {
    int base = (b-2)*1024 + tid*4;
    if (base + 3 < N) *(int4*)(cnt + base) = make_int4(0,0,0,0);
    else { for (int i=0;i<4;i++) if (base+i < N) cnt[base+i] = 0; }
  }
}

// ---- fused: proj1 (blockIdx%4 != 3) || hist (blockIdx%4 == 3). ----
// proj1: register-blocked GEMM, proj (bf16) = x @ W1', ss/st via 8-lane reduce.
// hist: 4-deep batched returning atomics (load x4 -> atomic x4 -> store x4).
__global__ void __launch_bounds__(256) k_fused1(
    const float* __restrict__ x, const float* __restrict__ W1,
    const float* __restrict__ a_src, const float* __restrict__ a_tgt,
    u16* __restrict__ projb, float* __restrict__ ss, float* __restrict__ st, int N,
    const int* __restrict__ ei, const int* __restrict__ flag,
    int* __restrict__ cnt, int* __restrict__ eoff, int E)
{
  __shared__ float Ws[128*64];
  int t = threadIdx.x;
  int rr = blockIdx.x & 3, kq = blockIdx.x >> 2;
  if (rr == 3){
    // --- hist path: 512 blocks, 4-deep batched ---
    int i64 = *flag;
    int S = (GRID_F1/4)*256;               // 131072
    int gid = kq*256 + t;
    for (int b = gid; b < E; b += 4*S){
      int e0=b, e1=b+S, e2=b+2*S, e3=b+3*S;
      int t0=0,t1=0,t2=0,t3=0;
      if (e0<E) t0 = i64 ? ei[2*E+2*e0] : ei[E+e0];
      if (e1<E) t1 = i64 ? ei[2*E+2*e1] : ei[E+e1];
      if (e2<E) t2 = i64 ? ei[2*E+2*e2] : ei[E+e2];
      if (e3<E) t3 = i64 ? ei[2*E+2*e3] : ei[E+e3];
      int o0=0,o1=0,o2=0,o3=0;
      if (e0<E) o0 = atomicAdd(cnt+t0,1);
      if (e1<E) o1 = atomicAdd(cnt+t1,1);
      if (e2<E) o2 = atomicAdd(cnt+t2,1);
      if (e3<E) o3 = atomicAdd(cnt+t3,1);
      if (e0<E) eoff[e0]=o0;
      if (e1<E) eoff[e1]=o1;
      if (e2<E) eoff[e2]=o2;
      if (e3<E) eoff[e3]=o3;
    }
    return;
  }
  // --- proj1 path: pidx in 0..1535 ---
  int pidx = 3*kq + rr;
  int ybase = (pidx & 1)*64;
  int xblk  = pidx >> 1;                 // 0..767
  for (int i = t; i < 128*64; i += 256){
    int f = i >> 6, jj = i & 63;
    int j = ybase + jj;
    Ws[i] = W1[((j>>5)<<12) + (f<<5) + (j&31)];
  }
  __syncthreads();
  int g = t & 15, slot = t >> 4;
  int col = ybase + g*4;
  float4 as = *(const float4*)(a_src + col);
  float4 at = *(const float4*)(a_tgt + col);
  for (int base = xblk*32; base < N; base += 768*32){
    int n0 = base + 2*slot, n1 = n0 + 1;
    bool v0 = n0 < N, v1 = n1 < N;
    int nc0 = v0 ? n0 : 0, nc1 = v1 ? n1 : 0;
    float4 acc0 = {0,0,0,0}, acc1 = {0,0,0,0};
    #pragma unroll 4
    for (int f = 0; f < 128; f += 4){
      float4 xa = *(const float4*)(x + (size_t)nc0*128 + f);
      float4 xb = *(const float4*)(x + (size_t)nc1*128 + f);
      const float4* wr = (const float4*)(Ws + f*64 + g*4);
      float4 w0 = wr[0], w1 = wr[16], w2 = wr[32], w3 = wr[48];
      fma4(acc0, xa.x, w0); fma4(acc0, xa.y, w1); fma4(acc0, xa.z, w2); fma4(acc0, xa.w, w3);
      fma4(acc1, xb.x, w0); fma4(acc1, xb.y, w1); fma4(acc1, xb.z, w2); fma4(acc1, xb.w, w3);
    }
    if (v0){
      uint2 p; p.x = f2bf(acc0.x) | (f2bf(acc0.y)<<16); p.y = f2bf(acc0.z) | (f2bf(acc0.w)<<16);
      *(uint2*)(projb + (size_t)n0*128 + col) = p;
    }
    if (v1){
      uint2 p; p.x = f2bf(acc1.x) | (f2bf(acc1.y)<<16); p.y = f2bf(acc1.z) | (f2bf(acc1.w)<<16);
      *(uint2*)(projb + (size_t)n1*128 + col) = p;
    }
    float ps0 = acc0.x*as.x + acc0.y*as.y + acc0.z*as.z + acc0.w*as.w;
    float pt0 = acc0.x*at.x + acc0.y*at.y + acc0.z*at.z + acc0.w*at.w;
    float ps1 = acc1.x*as.x + acc1.y*as.y + acc1.z*as.z + acc1.w*as.w;
    float pt1 = acc1.x*at.x + acc1.y*at.y + acc1.z*at.z + acc1.w*at.w;
    #pragma unroll
    for (int off=1; off<8; off<<=1){
      ps0 += __shfl_xor(ps0, off, 64); pt0 += __shfl_xor(pt0, off, 64);
      ps1 += __shfl_xor(ps1, off, 64); pt1 += __shfl_xor(pt1, off, 64);
    }
    if ((g&7)==0){
      int h = (ybase>>5) + (g>>3);
      if (v0){ ss[4*n0 + h] = ps0; st[4*n0 + h] = pt0; }
      if (v1){ ss[4*n1 + h] = ps1; st[4*n1 + h] = pt1; }
    }
  }
}

// ---- single-pass scan (decoupled last-block): partial rowptr + boff. ----
__global__ void __launch_bounds__(256) k_scan(const int* __restrict__ cnt,
    int* __restrict__ rowptr, int* __restrict__ bsum, int* __restrict__ boff,
    unsigned* __restrict__ done, int N, int NB){
  __shared__ int wsum[4];
  __shared__ int lastFlag;
  int tid = threadIdx.x, lane = tid & 63, wv = tid >> 6;
  int base = blockIdx.x*1024 + tid*4;
  int4 v = make_int4(0,0,0,0);
  if (base + 3 < N) v = *(const int4*)(cnt + base);
  else {
    if (base   < N) v.x = cnt[base];
    if (base+1 < N) v.y = cnt[base+1];
    if (base+2 < N) v.z = cnt[base+2];
  }
  int tsum = v.x+v.y+v.z+v.w;
  int inc = tsum;
  #pragma unroll
  for (int off=1; off<64; off<<=1){
    int o = __shfl_up(inc, off, 64);
    if (lane >= off) inc += o;
  }
  if (lane == 63) wsum[wv] = inc;
  __syncthreads();
  int wo = 0;
  #pragma unroll
  for (int w=0; w<4; w++) wo += (w < wv) ? wsum[w] : 0;
  int ex = wo + inc - tsum;
  int4 r; r.x = ex; r.y = ex+v.x; r.z = ex+v.x+v.y; r.w = ex+v.x+v.y+v.z;
  if (base + 3 < N) *(int4*)(rowptr + base) = r;
  else {
    if (base   < N) rowptr[base]   = r.x;
    if (base+1 < N) rowptr[base+1] = r.y;
    if (base+2 < N) rowptr[base+2] = r.z;
  }
  if (tid == 0){
    bsum[blockIdx.x] = wsum[0]+wsum[1]+wsum[2]+wsum[3];
    __threadfence();
    unsigned tk = atomicAdd(done, 1u);
    lastFlag = (tk == (unsigned)(NB-1));
  }
  __syncthreads();
  if (lastFlag){
    __threadfence();
    if (tid < 64){
      int vv = tid < NB ? bsum[tid] : 0;
      int ii = vv;
      #pragma unroll
      for (int off=1; off<64; off<<=1){
        int o = __shfl_up(ii, off, 64);
        if (tid >= off) ii += o;
      }
      if (tid < NB) boff[tid] = ii - vv;
    }
  }
}

// Atomic-free scatter: pos = rowptr[t]+boff[t>>10]+eoff[e].
__global__ void __launch_bounds__(256) k_scatter(const int* __restrict__ ei,
    const int* __restrict__ flag, const int* __restrict__ rowptr,
    const int* __restrict__ boff, const int* __restrict__ eoff,
    int* __restrict__ esrc, int E){
  int i64 = *flag;
  int stride = gridDim.x*256;
  for (int e = blockIdx.x*256 + threadIdx.x; e < E; e += stride){
    int s, t;
    if (i64){ s = ei[2*e]; t = ei[2*E + 2*e]; }
    else    { s = ei[e];   t = ei[E + e]; }
    esrc[rowptr[t] + boff[t>>10] + eoff[e]] = s;
  }
}

// One wave per node; lane owns cols {2*lane,2*lane+1}; 8-deep batched loads.
// Whole wave reads ONE 256B row per k-step (coalesced). Single pass (no
// segment-max: logits are O(5), exp cannot overflow). Emits ss2/st2 fused.
__global__ void __launch_bounds__(256) k_l1(
    const int* __restrict__ rowptr, const int* __restrict__ boff,
    const int* __restrict__ esrc,
    const float* __restrict__ ss, const float* __restrict__ st,
    const u16* __restrict__ projb, const float* __restrict__ b1,
    const float* __restrict__ wt, float* __restrict__ hbuf,
    float* __restrict__ ss2, float* __restrict__ st2, int N, int E)
{
  int lane = threadIdx.x & 63;
  int node = blockIdx.x*4 + (threadIdx.x>>6);
  if (node >= N) return;
  int beg = rowptr[node] + boff[node>>10];
  int np1 = node + 1;
  int end = (np1 == N) ? E : rowptr[np1] + boff[np1>>10];
  int h = lane & 3;
  float stv = st[4*node + h];
  float accx = 0.f, accy = 0.f, denom = 0.f;
  int hc = lane >> 4;
  const u16* myco = projb + 2*lane;
  for (int cbeg = beg; cbeg < end; cbeg += 16){
    int ne = end - cbeg; if (ne > 16) ne = 16;
    int e = cbeg + (lane>>2);
    float ex = 0.f; int sreg = 0;
    if (e < end){ sreg = esrc[e]; ex = __expf(lrelu(ss[4*sreg + h] + stv)); }
    denom += ex;
    if (ne == 16){
      #pragma unroll
      for (int half = 0; half < 2; ++half){
        const int kb = half*8;
        u32 w[8]; float eh[8];
        #pragma unroll
        for (int k=0;k<8;k++){
          int sl = __shfl(sreg, (kb+k)*4, 64);
          w[k] = *(const u32*)(myco + (size_t)sl*128);   // 8 loads in flight
        }
        #pragma unroll
        for (int k=0;k<8;k++) eh[k] = __shfl(ex, (kb+k)*4 + hc, 64);
        #pragma unroll
        for (int k=0;k<8;k++){ accx += bf_lo(w[k])*eh[k]; accy += bf_hi(w[k])*eh[k]; }
      }
    } else {
      for (int k=0;k<ne;k++){
        int   sl = __shfl(sreg, k*4, 64);
        float eh = __shfl(ex, k*4 + hc, 64);
        u32 w = *(const u32*)(myco + (size_t)sl*128);
        accx += bf_lo(w)*eh; accy += bf_hi(w)*eh;
      }
    }
  }
  #pragma unroll
  for (int off=4; off<64; off<<=1) denom += __shfl_xor(denom, off, 64);
  float d = __shfl(denom, hc, 64) + 1e-16f;
  float2 bb = *(const float2*)(b1 + 2*lane);
  float v0 = accx/d + bb.x;
  float v1 = accy/d + bb.y;
  float h0 = v0 > 0.f ? v0 : expm1f(v0);
  float h1 = v1 > 0.f ? v1 : expm1f(v1);
  *(float2*)(hbuf + (size_t)node*128 + 2*lane) = make_float2(h0, h1);
  float2 wsv = *(const float2*)(wt + 2*lane);
  float2 wtv = *(const float2*)(wt + 128 + 2*lane);
  float pss = h0*wsv.x + h1*wsv.y;
  float ptt = h0*wtv.x + h1*wtv.y;
  #pragma unroll
  for (int off=1; off<64; off<<=1){
    pss += __shfl_xor(pss, off, 64); ptt += __shfl_xor(ptt, off, 64);
  }
  if (lane == 0){ ss2[node] = pss; st2[node] = ptt; }
}

// Register-blocked GEMM: proj2 (bf16) = h @ W2. 20KB LDS.
__global__ void __launch_bounds__(256) k_proj2(
    const float* __restrict__ h, const float* __restrict__ W2,
    u16* __restrict__ projb2, int N)
{
  __shared__ float Ws[128*NCLASS];
  int t = threadIdx.x;
  for (int i = t; i < 128*NCLASS; i += 256) Ws[i] = W2[i];
  __syncthreads();
  if (t >= 250) return;
  int g = t % 10, slot = t / 10;
  int col = g*4;
  for (int base = blockIdx.x*50; base < N; base += gridDim.x*50){
    int n0 = base + 2*slot, n1 = n0 + 1;
    bool v0 = n0 < N, v1 = n1 < N;
    int nc0 = v0 ? n0 : 0, nc1 = v1 ? n1 : 0;
    float4 acc0 = {0,0,0,0}, acc1 = {0,0,0,0};
    #pragma unroll 4
    for (int f = 0; f < 128; f += 4){
      float4 xa = *(const float4*)(h + (size_t)nc0*128 + f);
      float4 xb = *(const float4*)(h + (size_t)nc1*128 + f);
      const float4* wr = (const float4*)(Ws + f*NCLASS + col);
      float4 w0 = wr[0], w1 = wr[10], w2 = wr[20], w3 = wr[30];
      fma4(acc0, xa.x, w0); fma4(acc0, xa.y, w1); fma4(acc0, xa.z, w2); fma4(acc0, xa.w, w3);
      fma4(acc1, xb.x, w0); fma4(acc1, xb.y, w1); fma4(acc1, xb.z, w2); fma4(acc1, xb.w, w3);
    }
    if (v0){
      uint2 p; p.x = f2bf(acc0.x) | (f2bf(acc0.y)<<16); p.y = f2bf(acc0.z) | (f2bf(acc0.w)<<16);
      *(uint2*)(projb2 + (size_t)n0*NCLASS + col) = p;
    }
    if (v1){
      uint2 p; p.x = f2bf(acc1.x) | (f2bf(acc1.y)<<16); p.y = f2bf(acc1.z) | (f2bf(acc1.w)<<16);
      *(uint2*)(projb2 + (size_t)n1*NCLASS + col) = p;
    }
  }
}

// One wave per node; lanes 0..39 own one class column; 8-deep batched loads.
__global__ void __launch_bounds__(256) k_l2(
    const int* __restrict__ rowptr, const int* __restrict__ boff,
    const int* __restrict__ esrc,
    const float* __restrict__ ss, const float* __restrict__ st,
    const u16* __restrict__ projb2, float* __restrict__ out, int N, int E)
{
  int lane = threadIdx.x & 63;
  int node = blockIdx.x*4 + (threadIdx.x>>6);
  if (node >= N) return;
  int beg = rowptr[node] + boff[node>>10];
  int np1 = node + 1;
  int end = (np1 == N) ? E : rowptr[np1] + boff[np1>>10];
  float stv = st[node];
  float acc = 0.f, denom = 0.f;
  const u16* myco = projb2 + lane;   // lanes>=40 read in-region garbage, discarded
  for (int cbeg = beg; cbeg < end; cbeg += 64){
    int ne = end - cbeg; if (ne > 64) ne = 64;
    int e = cbeg + lane;
    float ex = 0.f; int sreg = 0;
    if (e < end){ sreg = esrc[e]; ex = __expf(lrelu(ss[sreg] + stv)); }
    denom += ex;
    int k = 0;
    for (; k+8 <= ne; k += 8){
      u16 wv[8]; float ek[8];
      #pragma unroll
      for (int q=0;q<8;q++){
        int sl = __shfl(sreg, k+q, 64);
        wv[q] = myco[(size_t)sl*NCLASS];   // 8 loads in flight
      }
      #pragma unroll
      for (int q=0;q<8;q++) ek[q] = __shfl(ex, k+q, 64);
      #pragma unroll
      for (int q=0;q<8;q++) acc += bf1(wv[q])*ek[q];
    }
    for (; k < ne; k++){
      int   sl  = __shfl(sreg, k, 64);
      float exk = __shfl(ex, k, 64);
      acc += bf1(myco[(size_t)sl*NCLASS]) * exk;
    }
  }
  #pragma unroll
  for (int off=32; off; off>>=1) denom += __shfl_xor(denom, off, 64);
  float v = lane < NCLASS ? acc/(denom + 1e-16f) : -INFINITY;
  float m2 = v;
  #pragma unroll
  for (int off=32; off; off>>=1) m2 = fmaxf(m2, __shfl_xor(m2, off, 64));
  float sme = lane < NCLASS ? __expf(v - m2) : 0.f;
  #pragma unroll
  for (int off=32; off; off>>=1) sme += __shfl_xor(sme, off, 64);
  if (lane < NCLASS) out[(size_t)node*NCLASS + lane] = v - m2 - logf(sme);
}

extern "C" void kernel_launch(void* const* d_in, const int* in_sizes, int n_in,
                              void* d_out, int out_size, void* d_ws, size_t ws_size,
                              hipStream_t stream)
{
  const float* x   = (const float*)d_in[0];
  const int*   ei  = (const int*)d_in[2];
  const float* W1  = (const float*)d_in[3];
  const float* a1s = (const float*)d_in[4];
  const float* a1t = (const float*)d_in[5];
  const float* b1  = (const float*)d_in[6];
  const float* W2  = (const float*)d_in[7];
  const float* a2s = (const float*)d_in[8];
  const float* a2t = (const float*)d_in[9];
  float* out = (float*)d_out;
  const int N = in_sizes[0] / F_IN;      // 50000
  const int E = in_sizes[2] / 2;         // 800000
  const int NB = (N + 1023) / 1024;      // scan blocks (49, <=64)

  char* w = (char*)d_ws;
  float*    hbuf   = (float*)w;                        // N*128 f32
  u16*      projb  = (u16*)(hbuf + (size_t)N*128);     // N*128 bf16
  u16*      projb2 = projb;                            // N*40 bf16 (overlap)
  float*    ss1    = (float*)(projb + (size_t)N*128);  // 4N
  float*    st1    = ss1 + 4*(size_t)N;                // 4N
  float*    ss2    = st1 + 4*(size_t)N;                // N
  float*    st2    = ss2 + N;                          // N
  int*      rowptr = (int*)(st2 + N);                  // N (partial)
  int*      cnt    = rowptr + N + 4;                   // N
  int*      eoff   = cnt + N;                          // E
  int*      esrc   = eoff + E;                         // E
  int*      flag   = esrc + E;                         // 1
  float*    wt     = (float*)(flag + 4);               // 256
  int*      bsum   = (int*)(wt + 256);                 // <=64
  int*      boff   = bsum + 64;                        // <=64
  unsigned* done   = (unsigned*)(boff + 64);           // 1

  k_init<<<2+NB,256,0,stream>>>(ei, E, flag, done, cnt, N, W2, a2s, a2t, wt);
  k_fused1<<<GRID_F1,256,0,stream>>>(x, W1, a1s, a1t, projb, ss1, st1, N,
                                     ei, flag, cnt, eoff, E);
  k_scan<<<NB,256,0,stream>>>(cnt, rowptr, bsum, boff, done, N, NB);
  k_scatter<<<(E+1023)/1024,256,0,stream>>>(ei, flag, rowptr, boff, eoff, esrc, E);
  k_l1<<<(N+3)/4,256,0,stream>>>(rowptr, boff, esrc, ss1, st1, projb, b1, wt,
                                 hbuf, ss2, st2, N, E);
  k_proj2<<<(N+49)/50,256,0,stream>>>(hbuf, W2, projb2, N);
  k_l2<<<(N+3)/4,256,0,stream>>>(rowptr, boff, esrc, ss2, st2, projb2, out, N, E);
}

// Round 20
// 177.669 us; speedup vs baseline: 1.1299x; 1.0012x over previous
//
#include <hip/hip_runtime.h>
#include <math.h>

#define F_IN   128
#define NCLASS 40
#define ALPHA  0.2f
#define GRID_F1 2048   // fused proj1+hist grid: 3/4 proj1 (1536), 1/4 hist (512)

typedef unsigned int  u32;
typedef unsigned short u16;

__device__ __forceinline__ float lrelu(float v){ return v > 0.0f ? v : ALPHA*v; }
__device__ __forceinline__ void fma4(float4& a, float s, const float4& w){
  a.x += s*w.x; a.y += s*w.y; a.z += s*w.z; a.w += s*w.w;
}
__device__ __forceinline__ u32 f2bf(float f){
  u32 u = __float_as_uint(f);
  return (u + 0x7fffu + ((u>>16)&1u)) >> 16;
}
__device__ __forceinline__ float bf_lo(u32 w){ return __uint_as_float(w << 16); }
__device__ __forceinline__ float bf_hi(u32 w){ return __uint_as_float(w & 0xffff0000u); }
__device__ __forceinline__ float bf1(u16 w){ return __uint_as_float(((u32)w) << 16); }

// ---- init: block0 = dtype-detect + zero done, block1 = wt precompute,
//      blocks 2.. = zero cnt. ----
__global__ void __launch_bounds__(256) k_init(
    const int* __restrict__ ei, int E, int* __restrict__ flag,
    unsigned* __restrict__ done, int* __restrict__ cnt, int N,
    const float* __restrict__ W2, const float* __restrict__ a2s,
    const float* __restrict__ a2t, float* __restrict__ wt)
{
  int b = blockIdx.x, tid = threadIdx.x;
  if (b == 0){
    __shared__ int red[4];
    int n = E < 1000 ? E : 1000;
    int c = 0;
    for (int j = tid; j < n; j += 256) c += (ei[2*j+1]==0);
    #pragma unroll
    for (int off=32; off; off>>=1) c += __shfl_xor(c, off, 64);
    if ((tid&63)==0) red[tid>>6] = c;
    __syncthreads();
    if (tid==0) *flag = (red[0]+red[1]+red[2]+red[3]) > n/2 ? 1 : 0;
    if (tid==1) *done = 0u;
  } else if (b == 1){
    if (tid < 128){
      float s = 0.f, t = 0.f;
      for (int c=0;c<NCLASS;c++){ float w = W2[tid*NCLASS+c]; s += w*a2s[c]; t += w*a2t[c]; }
      wt[tid] = s; wt[128+tid] = t;
    }
  } else {
    int base = (b-2)*1024 + tid*4;
    if (base + 3 < N) *(int4*)(cnt + base) = make_int4(0,0,0,0);
    else { for (int i=0;i<4;i++) if (base+i < N) cnt[base+i] = 0; }
  }
}

// ---- fused: proj1 (blockIdx%4 != 3) || hist (blockIdx%4 == 3). ----
// proj1: register-blocked GEMM, proj (bf16) = x @ W1', ss/st via 8-lane reduce.
// hist: 4-deep batched returning atomics (load x4 -> atomic x4 -> store x4).
__global__ void __launch_bounds__(256) k_fused1(
    const float* __restrict__ x, const float* __restrict__ W1,
    const float* __restrict__ a_src, const float* __restrict__ a_tgt,
    u16* __restrict__ projb, float* __restrict__ ss, float* __restrict__ st, int N,
    const int* __restrict__ ei, const int* __restrict__ flag,
    int* __restrict__ cnt, int* __restrict__ eoff, int E)
{
  __shared__ float Ws[128*64];
  int t = threadIdx.x;
  int rr = blockIdx.x & 3, kq = blockIdx.x >> 2;
  if (rr == 3){
    // --- hist path: 512 blocks, 4-deep batched ---
    int i64 = *flag;
    int S = (GRID_F1/4)*256;               // 131072
    int gid = kq*256 + t;
    for (int b = gid; b < E; b += 4*S){
      int e0=b, e1=b+S, e2=b+2*S, e3=b+3*S;
      int t0=0,t1=0,t2=0,t3=0;
      if (e0<E) t0 = i64 ? ei[2*E+2*e0] : ei[E+e0];
      if (e1<E) t1 = i64 ? ei[2*E+2*e1] : ei[E+e1];
      if (e2<E) t2 = i64 ? ei[2*E+2*e2] : ei[E+e2];
      if (e3<E) t3 = i64 ? ei[2*E+2*e3] : ei[E+e3];
      int o0=0,o1=0,o2=0,o3=0;
      if (e0<E) o0 = atomicAdd(cnt+t0,1);
      if (e1<E) o1 = atomicAdd(cnt+t1,1);
      if (e2<E) o2 = atomicAdd(cnt+t2,1);
      if (e3<E) o3 = atomicAdd(cnt+t3,1);
      if (e0<E) eoff[e0]=o0;
      if (e1<E) eoff[e1]=o1;
      if (e2<E) eoff[e2]=o2;
      if (e3<E) eoff[e3]=o3;
    }
    return;
  }
  // --- proj1 path: pidx in 0..1535 ---
  int pidx = 3*kq + rr;
  int ybase = (pidx & 1)*64;
  int xblk  = pidx >> 1;                 // 0..767
  for (int i = t; i < 128*64; i += 256){
    int f = i >> 6, jj = i & 63;
    int j = ybase + jj;
    Ws[i] = W1[((j>>5)<<12) + (f<<5) + (j&31)];
  }
  __syncthreads();
  int g = t & 15, slot = t >> 4;
  int col = ybase + g*4;
  float4 as = *(const float4*)(a_src + col);
  float4 at = *(const float4*)(a_tgt + col);
  for (int base = xblk*32; base < N; base += 768*32){
    int n0 = base + 2*slot, n1 = n0 + 1;
    bool v0 = n0 < N, v1 = n1 < N;
    int nc0 = v0 ? n0 : 0, nc1 = v1 ? n1 : 0;
    float4 acc0 = {0,0,0,0}, acc1 = {0,0,0,0};
    #pragma unroll 4
    for (int f = 0; f < 128; f += 4){
      float4 xa = *(const float4*)(x + (size_t)nc0*128 + f);
      float4 xb = *(const float4*)(x + (size_t)nc1*128 + f);
      const float4* wr = (const float4*)(Ws + f*64 + g*4);
      float4 w0 = wr[0], w1 = wr[16], w2 = wr[32], w3 = wr[48];
      fma4(acc0, xa.x, w0); fma4(acc0, xa.y, w1); fma4(acc0, xa.z, w2); fma4(acc0, xa.w, w3);
      fma4(acc1, xb.x, w0); fma4(acc1, xb.y, w1); fma4(acc1, xb.z, w2); fma4(acc1, xb.w, w3);
    }
    if (v0){
      uint2 p; p.x = f2bf(acc0.x) | (f2bf(acc0.y)<<16); p.y = f2bf(acc0.z) | (f2bf(acc0.w)<<16);
      *(uint2*)(projb + (size_t)n0*128 + col) = p;
    }
    if (v1){
      uint2 p; p.x = f2bf(acc1.x) | (f2bf(acc1.y)<<16); p.y = f2bf(acc1.z) | (f2bf(acc1.w)<<16);
      *(uint2*)(projb + (size_t)n1*128 + col) = p;
    }
    float ps0 = acc0.x*as.x + acc0.y*as.y + acc0.z*as.z + acc0.w*as.w;
    float pt0 = acc0.x*at.x + acc0.y*at.y + acc0.z*at.z + acc0.w*at.w;
    float ps1 = acc1.x*as.x + acc1.y*as.y + acc1.z*as.z + acc1.w*as.w;
    float pt1 = acc1.x*at.x + acc1.y*at.y + acc1.z*at.z + acc1.w*at.w;
    #pragma unroll
    for (int off=1; off<8; off<<=1){
      ps0 += __shfl_xor(ps0, off, 64); pt0 += __shfl_xor(pt0, off, 64);
      ps1 += __shfl_xor(ps1, off, 64); pt1 += __shfl_xor(pt1, off, 64);
    }
    if ((g&7)==0){
      int h = (ybase>>5) + (g>>3);
      if (v0){ ss[4*n0 + h] = ps0; st[4*n0 + h] = pt0; }
      if (v1){ ss[4*n1 + h] = ps1; st[4*n1 + h] = pt1; }
    }
  }
}

// ---- single-pass scan (decoupled last-block): partial rowptr + boff. ----
__global__ void __launch_bounds__(256) k_scan(const int* __restrict__ cnt,
    int* __restrict__ rowptr, int* __restrict__ bsum, int* __restrict__ boff,
    unsigned* __restrict__ done, int N, int NB){
  __shared__ int wsum[4];
  __shared__ int lastFlag;
  int tid = threadIdx.x, lane = tid & 63, wv = tid >> 6;
  int base = blockIdx.x*1024 + tid*4;
  int4 v = make_int4(0,0,0,0);
  if (base + 3 < N) v = *(const int4*)(cnt + base);
  else {
    if (base   < N) v.x = cnt[base];
    if (base+1 < N) v.y = cnt[base+1];
    if (base+2 < N) v.z = cnt[base+2];
  }
  int tsum = v.x+v.y+v.z+v.w;
  int inc = tsum;
  #pragma unroll
  for (int off=1; off<64; off<<=1){
    int o = __shfl_up(inc, off, 64);
    if (lane >= off) inc += o;
  }
  if (lane == 63) wsum[wv] = inc;
  __syncthreads();
  int wo = 0;
  #pragma unroll
  for (int w=0; w<4; w++) wo += (w < wv) ? wsum[w] : 0;
  int ex = wo + inc - tsum;
  int4 r; r.x = ex; r.y = ex+v.x; r.z = ex+v.x+v.y; r.w = ex+v.x+v.y+v.z;
  if (base + 3 < N) *(int4*)(rowptr + base) = r;
  else {
    if (base   < N) rowptr[base]   = r.x;
    if (base+1 < N) rowptr[base+1] = r.y;
    if (base+2 < N) rowptr[base+2] = r.z;
  }
  if (tid == 0){
    bsum[blockIdx.x] = wsum[0]+wsum[1]+wsum[2]+wsum[3];
    __threadfence();
    unsigned tk = atomicAdd(done, 1u);
    lastFlag = (tk == (unsigned)(NB-1));
  }
  __syncthreads();
  if (lastFlag){
    __threadfence();
    if (tid < 64){
      int vv = tid < NB ? bsum[tid] : 0;
      int ii = vv;
      #pragma unroll
      for (int off=1; off<64; off<<=1){
        int o = __shfl_up(ii, off, 64);
        if (tid >= off) ii += o;
      }
      if (tid < NB) boff[tid] = ii - vv;
    }
  }
}

// Atomic-free scatter: pos = rowptr[t]+boff[t>>10]+eoff[e].
__global__ void __launch_bounds__(256) k_scatter(const int* __restrict__ ei,
    const int* __restrict__ flag, const int* __restrict__ rowptr,
    const int* __restrict__ boff, const int* __restrict__ eoff,
    int* __restrict__ esrc, int E){
  int i64 = *flag;
  int stride = gridDim.x*256;
  for (int e = blockIdx.x*256 + threadIdx.x; e < E; e += stride){
    int s, t;
    if (i64){ s = ei[2*e]; t = ei[2*E + 2*e]; }
    else    { s = ei[e];   t = ei[E + e]; }
    esrc[rowptr[t] + boff[t>>10] + eoff[e]] = s;
  }
}

// One wave per node; lane owns cols {2*lane,2*lane+1}; 8-deep batched loads.
// Whole wave reads ONE 256B row per k-step (coalesced). Single pass (no
// segment-max: logits are O(5), exp cannot overflow). Emits ss2/st2 fused.
__global__ void __launch_bounds__(256) k_l1(
    const int* __restrict__ rowptr, const int* __restrict__ boff,
    const int* __restrict__ esrc,
    const float* __restrict__ ss, const float* __restrict__ st,
    const u16* __restrict__ projb, const float* __restrict__ b1,
    const float* __restrict__ wt, float* __restrict__ hbuf,
    float* __restrict__ ss2, float* __restrict__ st2, int N, int E)
{
  int lane = threadIdx.x & 63;
  int node = blockIdx.x*4 + (threadIdx.x>>6);
  if (node >= N) return;
  int beg = rowptr[node] + boff[node>>10];
  int np1 = node + 1;
  int end = (np1 == N) ? E : rowptr[np1] + boff[np1>>10];
  int h = lane & 3;
  float stv = st[4*node + h];
  float accx = 0.f, accy = 0.f, denom = 0.f;
  int hc = lane >> 4;
  const u16* myco = projb + 2*lane;
  for (int cbeg = beg; cbeg < end; cbeg += 16){
    int ne = end - cbeg; if (ne > 16) ne = 16;
    int e = cbeg + (lane>>2);
    float ex = 0.f; int sreg = 0;
    if (e < end){ sreg = esrc[e]; ex = __expf(lrelu(ss[4*sreg + h] + stv)); }
    denom += ex;
    if (ne == 16){
      #pragma unroll
      for (int half = 0; half < 2; ++half){
        const int kb = half*8;
        u32 w[8]; float eh[8];
        #pragma unroll
        for (int k=0;k<8;k++){
          int sl = __shfl(sreg, (kb+k)*4, 64);
          w[k] = *(const u32*)(myco + (size_t)sl*128);   // 8 loads in flight
        }
        #pragma unroll
        for (int k=0;k<8;k++) eh[k] = __shfl(ex, (kb+k)*4 + hc, 64);
        #pragma unroll
        for (int k=0;k<8;k++){ accx += bf_lo(w[k])*eh[k]; accy += bf_hi(w[k])*eh[k]; }
      }
    } else {
      for (int k=0;k<ne;k++){
        int   sl = __shfl(sreg, k*4, 64);
        float eh = __shfl(ex, k*4 + hc, 64);
        u32 w = *(const u32*)(myco + (size_t)sl*128);
        accx += bf_lo(w)*eh; accy += bf_hi(w)*eh;
      }
    }
  }
  #pragma unroll
  for (int off=4; off<64; off<<=1) denom += __shfl_xor(denom, off, 64);
  float d = __shfl(denom, hc, 64) + 1e-16f;
  float2 bb = *(const float2*)(b1 + 2*lane);
  float v0 = accx/d + bb.x;
  float v1 = accy/d + bb.y;
  float h0 = v0 > 0.f ? v0 : expm1f(v0);
  float h1 = v1 > 0.f ? v1 : expm1f(v1);
  *(float2*)(hbuf + (size_t)node*128 + 2*lane) = make_float2(h0, h1);
  float2 wsv = *(const float2*)(wt + 2*lane);
  float2 wtv = *(const float2*)(wt + 128 + 2*lane);
  float pss = h0*wsv.x + h1*wsv.y;
  float ptt = h0*wtv.x + h1*wtv.y;
  #pragma unroll
  for (int off=1; off<64; off<<=1){
    pss += __shfl_xor(pss, off, 64); ptt += __shfl_xor(ptt, off, 64);
  }
  if (lane == 0){ ss2[node] = pss; st2[node] = ptt; }
}

// Register-blocked GEMM: proj2 (bf16) = h @ W2. 20KB LDS.
__global__ void __launch_bounds__(256) k_proj2(
    const float* __restrict__ h, const float* __restrict__ W2,
    u16* __restrict__ projb2, int N)
{
  __shared__ float Ws[128*NCLASS];
  int t = threadIdx.x;
  for (int i = t; i < 128*NCLASS; i += 256) Ws[i] = W2[i];
  __syncthreads();
  if (t >= 250) return;
  int g = t % 10, slot = t / 10;
  int col = g*4;
  for (int base = blockIdx.x*50; base < N; base += gridDim.x*50){
    int n0 = base + 2*slot, n1 = n0 + 1;
    bool v0 = n0 < N, v1 = n1 < N;
    int nc0 = v0 ? n0 : 0, nc1 = v1 ? n1 : 0;
    float4 acc0 = {0,0,0,0}, acc1 = {0,0,0,0};
    #pragma unroll 4
    for (int f = 0; f < 128; f += 4){
      float4 xa = *(const float4*)(h + (size_t)nc0*128 + f);
      float4 xb = *(const float4*)(h + (size_t)nc1*128 + f);
      const float4* wr = (const float4*)(Ws + f*NCLASS + col);
      float4 w0 = wr[0], w1 = wr[10], w2 = wr[20], w3 = wr[30];
      fma4(acc0, xa.x, w0); fma4(acc0, xa.y, w1); fma4(acc0, xa.z, w2); fma4(acc0, xa.w, w3);
      fma4(acc1, xb.x, w0); fma4(acc1, xb.y, w1); fma4(acc1, xb.z, w2); fma4(acc1, xb.w, w3);
    }
    if (v0){
      uint2 p; p.x = f2bf(acc0.x) | (f2bf(acc0.y)<<16); p.y = f2bf(acc0.z) | (f2bf(acc0.w)<<16);
      *(uint2*)(projb2 + (size_t)n0*NCLASS + col) = p;
    }
    if (v1){
      uint2 p; p.x = f2bf(acc1.x) | (f2bf(acc1.y)<<16); p.y = f2bf(acc1.z) | (f2bf(acc1.w)<<16);
      *(uint2*)(projb2 + (size_t)n1*NCLASS + col) = p;
    }
  }
}

// One wave per node; lanes 0..39 own one class column; 8-deep batched loads.
__global__ void __launch_bounds__(256) k_l2(
    const int* __restrict__ rowptr, const int* __restrict__ boff,
    const int* __restrict__ esrc,
    const float* __restrict__ ss, const float* __restrict__ st,
    const u16* __restrict__ projb2, float* __restrict__ out, int N, int E)
{
  int lane = threadIdx.x & 63;
  int node = blockIdx.x*4 + (threadIdx.x>>6);
  if (node >= N) return;
  int beg = rowptr[node] + boff[node>>10];
  int np1 = node + 1;
  int end = (np1 == N) ? E : rowptr[np1] + boff[np1>>10];
  float stv = st[node];
  float acc = 0.f, denom = 0.f;
  const u16* myco = projb2 + lane;   // lanes>=40 read in-region garbage, discarded
  for (int cbeg = beg; cbeg < end; cbeg += 64){
    int ne = end - cbeg; if (ne > 64) ne = 64;
    int e = cbeg + lane;
    float ex = 0.f; int sreg = 0;
    if (e < end){ sreg = esrc[e]; ex = __expf(lrelu(ss[sreg] + stv)); }
    denom += ex;
    int k = 0;
    for (; k+8 <= ne; k += 8){
      u16 wv[8]; float ek[8];
      #pragma unroll
      for (int q=0;q<8;q++){
        int sl = __shfl(sreg, k+q, 64);
        wv[q] = myco[(size_t)sl*NCLASS];   // 8 loads in flight
      }
      #pragma unroll
      for (int q=0;q<8;q++) ek[q] = __shfl(ex, k+q, 64);
      #pragma unroll
      for (int q=0;q<8;q++) acc += bf1(wv[q])*ek[q];
    }
    for (; k < ne; k++){
      int   sl  = __shfl(sreg, k, 64);
      float exk = __shfl(ex, k, 64);
      acc += bf1(myco[(size_t)sl*NCLASS]) * exk;
    }
  }
  #pragma unroll
  for (int off=32; off; off>>=1) denom += __shfl_xor(denom, off, 64);
  float v = lane < NCLASS ? acc/(denom + 1e-16f) : -INFINITY;
  float m2 = v;
  #pragma unroll
  for (int off=32; off; off>>=1) m2 = fmaxf(m2, __shfl_xor(m2, off, 64));
  float sme = lane < NCLASS ? __expf(v - m2) : 0.f;
  #pragma unroll
  for (int off=32; off; off>>=1) sme += __shfl_xor(sme, off, 64);
  if (lane < NCLASS) out[(size_t)node*NCLASS + lane] = v - m2 - logf(sme);
}

extern "C" void kernel_launch(void* const* d_in, const int* in_sizes, int n_in,
                              void* d_out, int out_size, void* d_ws, size_t ws_size,
                              hipStream_t stream)
{
  const float* x   = (const float*)d_in[0];
  const int*   ei  = (const int*)d_in[2];
  const float* W1  = (const float*)d_in[3];
  const float* a1s = (const float*)d_in[4];
  const float* a1t = (const float*)d_in[5];
  const float* b1  = (const float*)d_in[6];
  const float* W2  = (const float*)d_in[7];
  const float* a2s = (const float*)d_in[8];
  const float* a2t = (const float*)d_in[9];
  float* out = (float*)d_out;
  const int N = in_sizes[0] / F_IN;      // 50000
  const int E = in_sizes[2] / 2;         // 800000
  const int NB = (N + 1023) / 1024;      // scan blocks (49, <=64)

  char* w = (char*)d_ws;
  float*    hbuf   = (float*)w;                        // N*128 f32
  u16*      projb  = (u16*)(hbuf + (size_t)N*128);     // N*128 bf16
  u16*      projb2 = projb;                            // N*40 bf16 (overlap)
  float*    ss1    = (float*)(projb + (size_t)N*128);  // 4N
  float*    st1    = ss1 + 4*(size_t)N;                // 4N
  float*    ss2    = st1 + 4*(size_t)N;                // N
  float*    st2    = ss2 + N;                          // N
  int*      rowptr = (int*)(st2 + N);                  // N (partial)
  int*      cnt    = rowptr + N + 4;                   // N
  int*      eoff   = cnt + N;                          // E
  int*      esrc   = eoff + E;                         // E
  int*      flag   = esrc + E;                         // 1
  float*    wt     = (float*)(flag + 4);               // 256
  int*      bsum   = (int*)(wt + 256);                 // <=64
  int*      boff   = bsum + 64;                        // <=64
  unsigned* done   = (unsigned*)(boff + 64);           // 1

  k_init<<<2+NB,256,0,stream>>>(ei, E, flag, done, cnt, N, W2, a2s, a2t, wt);
  k_fused1<<<GRID_F1,256,0,stream>>>(x, W1, a1s, a1t, projb, ss1, st1, N,
                                     ei, flag, cnt, eoff, E);
  k_scan<<<NB,256,0,stream>>>(cnt, rowptr, bsum, boff, done, N, NB);
  k_scatter<<<(E+1023)/1024,256,0,stream>>>(ei, flag, rowptr, boff, eoff, esrc, E);
  k_l1<<<(N+3)/4,256,0,stream>>>(rowptr, boff, esrc, ss1, st1, projb, b1, wt,
                                 hbuf, ss2, st2, N, E);
  k_proj2<<<(N+49)/50,256,0,stream>>>(hbuf, W2, projb2, N);
  k_l2<<<(N+3)/4,256,0,stream>>>(rowptr, boff, esrc, ss2, st2, projb2, out, N, E);
}